// Round 2
// 658.558 us; speedup vs baseline: 1.0741x; 1.0741x over previous
//
#include <hip/hip_runtime.h>
#include <math.h>

#define BB 4
#define TT 1024
#define DM 1024
#define NH 16
#define HD 64
#define DFF 4096
#define N3 3072

typedef unsigned short u16;
typedef __attribute__((ext_vector_type(4))) float f32x4;
typedef __attribute__((ext_vector_type(8))) short s16x8;

__device__ __forceinline__ u16 f2bf(float f) {
    union { float f; unsigned u; } v; v.f = f;
    unsigned u = v.u;
    u += 0x7fffu + ((u >> 16) & 1u);
    return (u16)(u >> 16);
}
__device__ __forceinline__ float bf2f(u16 h) {
    union { unsigned u; float f; } v; v.u = ((unsigned)h) << 16;
    return v.f;
}

__device__ __forceinline__ void async_copy16(const void* g, void* l) {
    __builtin_amdgcn_global_load_lds(
        (const __attribute__((address_space(1))) unsigned int*)g,
        (__attribute__((address_space(3))) unsigned int*)l, 16, 0, 0);
}

// ---------------- convert fp32 -> bf16 ----------------
__global__ __launch_bounds__(256) void cvt_kernel(const float* __restrict__ in,
                                                  u16* __restrict__ out, int n) {
    int i = (blockIdx.x * 256 + threadIdx.x) * 4;
    if (i + 3 < n) {
        out[i + 0] = f2bf(in[i + 0]);
        out[i + 1] = f2bf(in[i + 1]);
        out[i + 2] = f2bf(in[i + 2]);
        out[i + 3] = f2bf(in[i + 3]);
    }
}

// ---------------- tiled transpose + convert: out[c][r] = in[r][c] ----------------
template<int TIN>
__global__ __launch_bounds__(256) void transpose_kernel(const void* __restrict__ inv,
                                                        u16* __restrict__ out, int R, int C) {
    __shared__ float tile[32][33];
    const float* inF = (const float*)inv;
    const u16* inH = (const u16*)inv;
    size_t boff = (size_t)blockIdx.z * R * C;
    int c0 = blockIdx.x * 32, r0 = blockIdx.y * 32;
    int tx = threadIdx.x & 31, ty = threadIdx.x >> 5;
    for (int i = 0; i < 4; i++) {
        int r = r0 + ty + i * 8, c = c0 + tx;
        float v = (TIN == 0) ? inF[boff + (size_t)r * C + c] : bf2f(inH[boff + (size_t)r * C + c]);
        tile[ty + i * 8][tx] = v;
    }
    __syncthreads();
    for (int i = 0; i < 4; i++) {
        int rr = r0 + tx, cc = c0 + ty + i * 8;
        out[boff + (size_t)cc * R + rr] = f2bf(tile[tx][ty + i * 8]);
    }
}

// ---------------- 256x256-tile bf16 MFMA GEMM, 4-deep pipelined ----------------
// C = A[M][Kstride] @ BT[N][Kstride]^T over K-range [blockIdx.z*NT*32, +NT*32)
// 512 threads = 8 waves (2 M x 4 N), per-wave output 128x64 (acc[8][4]).
// LDS: 4 circular buffers x (A 256x32 + B 256x32) bf16 = 128 KiB.
// Pipeline: compute tile t while t+1..t+3 in flight (global_load_lds);
// entry gate = s_waitcnt vmcnt(8) + ONE s_barrier per tile (counted, never
// drained to 0 until the last-2-tile epilogue peel: 8 -> 4 -> 0).
// LDS swizzle: 16B chunk index ^= (row & 3), applied BOTH on the pre-swizzled
// global source address (global_load_lds dest is linear) and on ds_read.
// EPI: 1 = qkv head-major scatter + bias; 2 = exact gelu + bias, bf16 store;
//      3 = split-K fp32 partial store (no bias).
template<int EPI, int NT>
__global__ __launch_bounds__(512, 2) void gemm256_kernel(const u16* __restrict__ A,
                                                         const u16* __restrict__ BT,
                                                         const float* __restrict__ bias,
                                                         void* __restrict__ out0v,
                                                         u16* __restrict__ out1,
                                                         u16* __restrict__ out2,
                                                         int M, int N, int Kstride) {
    __shared__ u16 As[4][8192];
    __shared__ u16 Bs[4][8192];
    const int tid = threadIdx.x;
    const int lane = tid & 63;
    const int wave = tid >> 6;
    const int quad = lane >> 4;
    const int l15 = lane & 15;
    const int wm = wave >> 2;   // 0..1 (M half)
    const int wn = wave & 3;    // 0..3 (N quarter)
    const int m0 = blockIdx.y * 256;
    const int n0 = blockIdx.x * 256;
    const int koff = blockIdx.z * (NT * 32);

    // ---- staging addresses: each thread stages 2x16B of A and 2x16B of B per tile.
    // LDS dest is LINEAR (wave-uniform base + lane*16); the swizzle is applied by
    // permuting the global SOURCE chunk within each 64B row (involution).
    const int srow = wave * 32 + (lane >> 2);                     // 0..255 over (wave,j)
    const int schunk = ((lane & 3) ^ ((lane >> 2) & 3)) * 8;      // swizzled 16B chunk
    const u16* aG0 = A + (size_t)(m0 + srow) * Kstride + koff + schunk;
    const u16* aG1 = aG0 + (size_t)16 * Kstride;
    const u16* bG0 = BT + (size_t)(n0 + srow) * Kstride + koff + schunk;
    const u16* bG1 = bG0 + (size_t)16 * Kstride;
    const int ldst0 = wave * 1024;        // u16 index of this wave's 1KB dest (j=0)
    const int ldst1 = wave * 1024 + 512;  // j=1

#define STAGE_A(t) { int kk_ = (t) * 32; \
    async_copy16(aG0 + kk_, &As[(t) & 3][ldst0]); \
    async_copy16(aG1 + kk_, &As[(t) & 3][ldst1]); }
#define STAGE_B(t) { int kk_ = (t) * 32; \
    async_copy16(bG0 + kk_, &Bs[(t) & 3][ldst0]); \
    async_copy16(bG1 + kk_, &Bs[(t) & 3][ldst1]); }

    // ---- fragment read bases (swizzled: chunk ^= row&3, row&3 == l15&3 here)
    const int swq = (quad ^ (l15 & 3)) * 8;
    const int abase = (wm * 128 + l15) * 32 + swq;
    const int bbase = (wn * 64 + l15) * 32 + swq;

    f32x4 acc[8][4] = {};

    // ---- prologue: stage tiles 0,1,2 (12 loads outstanding per thread)
    STAGE_A(0); STAGE_B(0);
    STAGE_A(1); STAGE_B(1);
    STAGE_A(2); STAGE_B(2);

#pragma unroll 1
    for (int t = 0; t < NT; ++t) {
        // entry gate: guarantee tile t landed; keep up to 2 future tiles in flight
        if (t < NT - 2)       asm volatile("s_waitcnt vmcnt(8)" ::: "memory");
        else if (t == NT - 2) asm volatile("s_waitcnt vmcnt(4)" ::: "memory");
        else                  asm volatile("s_waitcnt vmcnt(0)" ::: "memory");
        asm volatile("" ::: "memory");
        __builtin_amdgcn_s_barrier();
        asm volatile("" ::: "memory");

        const u16* as = As[t & 3];
        const u16* bs = Bs[t & 3];

        s16x8 bfr[4];
#pragma unroll
        for (int j = 0; j < 4; j++)
            bfr[j] = *(const s16x8*)&bs[bbase + j * 512];
        s16x8 afr[4];
#pragma unroll
        for (int i = 0; i < 4; i++)
            afr[i] = *(const s16x8*)&as[abase + i * 512];
        if (t + 3 < NT) STAGE_A(t + 3);   // into buf (t+3)&3 == (t-1)&3, freed at t-entry barrier
        __builtin_amdgcn_s_setprio(1);
#pragma unroll
        for (int i = 0; i < 4; i++)
#pragma unroll
            for (int j = 0; j < 4; j++)
                acc[i][j] = __builtin_amdgcn_mfma_f32_16x16x32_bf16(afr[i], bfr[j], acc[i][j], 0, 0, 0);
        __builtin_amdgcn_s_setprio(0);
#pragma unroll
        for (int i = 0; i < 4; i++)
            afr[i] = *(const s16x8*)&as[abase + 2048 + i * 512];
        if (t + 3 < NT) STAGE_B(t + 3);
        __builtin_amdgcn_s_setprio(1);
#pragma unroll
        for (int i = 0; i < 4; i++)
#pragma unroll
            for (int j = 0; j < 4; j++)
                acc[i + 4][j] = __builtin_amdgcn_mfma_f32_16x16x32_bf16(afr[i], bfr[j], acc[i + 4][j], 0, 0, 0);
        __builtin_amdgcn_s_setprio(0);
    }
#undef STAGE_A
#undef STAGE_B

    // ---- epilogue
    const size_t MN = (size_t)M * N;
#pragma unroll
    for (int i = 0; i < 8; i++) {
#pragma unroll
        for (int j = 0; j < 4; j++) {
            f32x4 c = acc[i][j];
            int gn = n0 + wn * 64 + j * 16 + l15;
            float bv = (EPI == 3) ? 0.f : bias[gn];
#pragma unroll
            for (int r = 0; r < 4; r++) {
                int gm = m0 + wm * 128 + i * 16 + quad * 4 + r;
                float v = c[r] + bv;
                if (EPI == 2) {
                    v = 0.5f * v * (1.f + erff(v * 0.70710678118f));
                    ((u16*)out0v)[(size_t)gm * N + gn] = f2bf(v);
                } else if (EPI == 3) {
                    ((float*)out0v)[(size_t)blockIdx.z * MN + (size_t)gm * N + gn] = v;
                } else {  // EPI == 1: qkv head-major scatter
                    int which = gn >> 10, h = (gn >> 6) & 15, d = gn & 63;
                    int bb = gm >> 10, tq = gm & 1023;
                    u16* dst = (which == 0) ? (u16*)out0v : ((which == 1) ? out1 : out2);
                    dst[((size_t)(bb * NH + h) * TT + tq) * HD + d] = f2bf(v);
                }
            }
        }
    }
}

// ---------------- attention: 512 threads = 8 waves, each wave owns 128 keys ----------------
__global__ __launch_bounds__(512) void attn_kernel(const u16* __restrict__ Qb,
                                                   const u16* __restrict__ Kb,
                                                   const u16* __restrict__ VTb,
                                                   const float* __restrict__ rel_bias,
                                                   const float* __restrict__ temp_p,
                                                   float* __restrict__ probs_out,
                                                   u16* __restrict__ attn_out) {
    __shared__ __align__(16) u16 Qs[16 * 72];
    __shared__ __align__(16) u16 Ps[16 * 1032];   // reused as float Op[8][16][64] later
    __shared__ float red[2][8][16];
    __shared__ float RB[1040];

    const int tid = threadIdx.x;
    const int lane = tid & 63, wave = tid >> 6, quad = lane >> 4, l15 = lane & 15;
    const int q0 = blockIdx.x * 16;
    const int h = blockIdx.y, b = blockIdx.z;
    const int bh = b * NH + h;
    const size_t headoff = (size_t)bh * TT * HD;

    float temp = fmaxf(temp_p[0], 0.01f);
    const float itemp = 1.f / temp;

    // stage rel_bias slice: indices [1008-q0, 2046-q0] of this head's row
    for (int i = tid; i < 1039; i += 512)
        RB[i] = rel_bias[h * 2047 + (1008 - q0) + i];
    if (tid < 256) {  // 16x64 Q tile
        int row = tid >> 4, col = (tid & 15) * 4;
        const u16* srcp = Qb + headoff + (size_t)(q0 + row) * HD + col;
        *(uint2*)&Qs[row * 72 + col] = *(const uint2*)srcp;
    }
    __syncthreads();

    // ---- S = Q K^T * (1/temp) + rel_bias ----
    s16x8 a0 = *(const s16x8*)&Qs[l15 * 72 + quad * 8];
    s16x8 a1 = *(const s16x8*)&Qs[l15 * 72 + 32 + quad * 8];
    f32x4 s[8];
    const u16* Kh = Kb + headoff;
#pragma unroll
    for (int nt = 0; nt < 8; nt++) {
        int key = wave * 128 + nt * 16 + l15;
        const u16* kp = Kh + (size_t)key * HD;
        s16x8 b0 = *(const s16x8*)(kp + quad * 8);
        s16x8 b1 = *(const s16x8*)(kp + 32 + quad * 8);
        f32x4 acc = {};
        acc = __builtin_amdgcn_mfma_f32_16x16x32_bf16(a0, b0, acc, 0, 0, 0);
        acc = __builtin_amdgcn_mfma_f32_16x16x32_bf16(a1, b1, acc, 0, 0, 0);
#pragma unroll
        for (int r = 0; r < 4; r++)
            acc[r] = acc[r] * itemp + RB[key - (quad * 4 + r) + 15];
        s[nt] = acc;
    }

    // ---- row max ----
    float lm[4];
#pragma unroll
    for (int r = 0; r < 4; r++) {
        float m = s[0][r];
#pragma unroll
        for (int nt = 1; nt < 8; nt++) m = fmaxf(m, s[nt][r]);
        for (int off = 8; off >= 1; off >>= 1) m = fmaxf(m, __shfl_xor(m, off));
        lm[r] = m;
    }
    if (l15 == 0)
        for (int r = 0; r < 4; r++) red[0][wave][quad * 4 + r] = lm[r];
    __syncthreads();
    float rm[4];
#pragma unroll
    for (int r = 0; r < 4; r++) {
        int row = quad * 4 + r;
        float m = red[0][0][row];
#pragma unroll
        for (int w = 1; w < 8; w++) m = fmaxf(m, red[0][w][row]);
        rm[r] = m;
    }

    // ---- exp + row sum ----
    float ls[4] = {0.f, 0.f, 0.f, 0.f};
#pragma unroll
    for (int nt = 0; nt < 8; nt++)
#pragma unroll
        for (int r = 0; r < 4; r++) {
            float p = __expf(s[nt][r] - rm[r]);
            s[nt][r] = p;
            ls[r] += p;
        }
#pragma unroll
    for (int r = 0; r < 4; r++) {
        float v = ls[r];
        for (int off = 8; off >= 1; off >>= 1) v += __shfl_xor(v, off);
        ls[r] = v;
    }
    if (l15 == 0)
        for (int r = 0; r < 4; r++) red[1][wave][quad * 4 + r] = ls[r];
    __syncthreads();
    float inv[4];
#pragma unroll
    for (int r = 0; r < 4; r++) {
        int row = quad * 4 + r;
        float v = red[1][0][row];
#pragma unroll
        for (int w = 1; w < 8; w++) v += red[1][w][row];
        inv[r] = 1.f / v;
    }

    // ---- write normalized probs (fp32 to d_out) + normalized bf16 P into LDS ----
    float* prow = probs_out + ((size_t)bh * TT + q0) * TT;
#pragma unroll
    for (int nt = 0; nt < 8; nt++) {
        int key = wave * 128 + nt * 16 + l15;
#pragma unroll
        for (int r = 0; r < 4; r++) {
            int row = quad * 4 + r;
            float pn = s[nt][r] * inv[r];
            prow[(size_t)row * TT + key] = pn;
            Ps[row * 1032 + key] = f2bf(pn);
        }
    }
    __syncthreads();

    // ---- O = P V over this wave's 128-key slab ----
    f32x4 o[4] = {};
    const u16* Vh = VTb + headoff;
#pragma unroll
    for (int ks = 0; ks < 4; ks++) {
        int k0 = wave * 128 + ks * 32;
        s16x8 pa = *(const s16x8*)&Ps[l15 * 1032 + k0 + quad * 8];
#pragma unroll
        for (int nt = 0; nt < 4; nt++) {
            int d = nt * 16 + l15;
            s16x8 vb = *(const s16x8*)(Vh + (size_t)d * TT + k0 + quad * 8);
            o[nt] = __builtin_amdgcn_mfma_f32_16x16x32_bf16(pa, vb, o[nt], 0, 0, 0);
        }
    }
    __syncthreads();  // all waves done reading Ps
    float* OpF = (float*)Ps;  // [8][16][64]
#pragma unroll
    for (int nt = 0; nt < 4; nt++)
#pragma unroll
        for (int r = 0; r < 4; r++)
            OpF[(wave * 16 + quad * 4 + r) * 64 + nt * 16 + l15] = o[nt][r];
    __syncthreads();

    {
        int m = tid >> 5, dc = (tid & 31) * 2;
        float a0v = 0.f, a1v = 0.f;
#pragma unroll
        for (int w = 0; w < 8; w++) {
            a0v += OpF[(w * 16 + m) * 64 + dc];
            a1v += OpF[(w * 16 + m) * 64 + dc + 1];
        }
        u16 pk[2] = {f2bf(a0v), f2bf(a1v)};
        *(unsigned*)&attn_out[((size_t)(b * TT + q0 + m)) * DM + h * HD + dc] = *(unsigned*)pk;
    }
}

// ---------------- layernorm with fused split-K reduce + bias ----------------
// MODE 0: x = LN(src_f32 + (biasN + sum_kz part)) -> bf16         (LN1, KS=2)
// MODE 1: y = LN(x_bf + scale*(biasN + sum_kz part)) -> fp32      (LN2, KS=4)
template<int MODE, int KS>
__global__ __launch_bounds__(256) void ln_kernel(const float* __restrict__ af32,
                                                 const u16* __restrict__ abf,
                                                 const float* __restrict__ part,
                                                 const float* __restrict__ biasN,
                                                 const float* __restrict__ scale_p,
                                                 const float* __restrict__ gamma,
                                                 const float* __restrict__ beta,
                                                 float* __restrict__ outf,
                                                 u16* __restrict__ outbf) {
    __shared__ float red[2][4];
    const size_t MN = (size_t)BB * TT * DM;
    int row = blockIdx.x;
    int tid = threadIdx.x;
    float sc = (MODE == 1) ? scale_p[0] : 1.f;
    int c0 = tid * 4;
    size_t base = (size_t)row * DM + c0;
    float4 a = *(const float4*)(biasN + c0);
    float acc[4] = {a.x, a.y, a.z, a.w};
#pragma unroll
    for (int kz = 0; kz < KS; kz++) {
        float4 p = *(const float4*)(part + kz * MN + base);
        acc[0] += p.x; acc[1] += p.y; acc[2] += p.z; acc[3] += p.w;
    }
    float x[4];
#pragma unroll
    for (int c = 0; c < 4; c++) {
        float b0 = (MODE == 0) ? af32[base + c] : bf2f(abf[base + c]);
        x[c] = b0 + sc * acc[c];
    }
    float s = x[0] + x[1] + x[2] + x[3];
    float sq = x[0] * x[0] + x[1] * x[1] + x[2] * x[2] + x[3] * x[3];
    for (int off = 32; off >= 1; off >>= 1) {
        s += __shfl_xor(s, off);
        sq += __shfl_xor(sq, off);
    }
    int wave = tid >> 6;
    if ((tid & 63) == 0) {
        red[0][wave] = s;
        red[1][wave] = sq;
    }
    __syncthreads();
    s = red[0][0] + red[0][1] + red[0][2] + red[0][3];
    sq = red[1][0] + red[1][1] + red[1][2] + red[1][3];
    float mu = s * (1.f / DM);
    float var = sq * (1.f / DM) - mu * mu;
    float rs = rsqrtf(var + 1e-5f);
#pragma unroll
    for (int c = 0; c < 4; c++) {
        float y = (x[c] - mu) * rs * gamma[c0 + c] + beta[c0 + c];
        if (MODE == 0) outbf[base + c] = f2bf(y);
        else outf[base + c] = y;
    }
}

// ---------------- workspace layout (bytes) ----------------
#define OFF_SRCBF 0UL
#define OFF_WQKVT 8388608UL
#define OFF_WOT 14680064UL
#define OFF_W1T 16777216UL
#define OFF_W2T 25165824UL
#define OFF_Q 33554432UL
#define OFF_K 41943040UL
#define OFF_V 50331648UL
#define OFF_VT 58720256UL
#define OFF_ATTNO 67108864UL
#define OFF_XBF 83886080UL
#define OFF_H1 92274688UL
#define OFF_PART 134217728UL   // 4 x 16MB fp32 partials (reused proj->ff2)

extern "C" void kernel_launch(void* const* d_in, const int* in_sizes, int n_in,
                              void* d_out, int out_size, void* d_ws, size_t ws_size,
                              hipStream_t stream) {
    const float* src = (const float*)d_in[0];
    const float* Wqkv = (const float*)d_in[1];
    const float* bqkv = (const float*)d_in[2];
    const float* Wo = (const float*)d_in[3];
    const float* bo = (const float*)d_in[4];
    const float* relb = (const float*)d_in[5];
    const float* temp = (const float*)d_in[6];
    const float* W1 = (const float*)d_in[7];
    const float* b1 = (const float*)d_in[8];
    const float* W2 = (const float*)d_in[9];
    const float* b2 = (const float*)d_in[10];
    const float* ffs = (const float*)d_in[11];
    const float* g1 = (const float*)d_in[12];
    const float* be1 = (const float*)d_in[13];
    const float* g2 = (const float*)d_in[14];
    const float* be2 = (const float*)d_in[15];

    char* ws = (char*)d_ws;
    u16* srcbf = (u16*)(ws + OFF_SRCBF);
    u16* WqkvT = (u16*)(ws + OFF_WQKVT);
    u16* WoT = (u16*)(ws + OFF_WOT);
    u16* W1T = (u16*)(ws + OFF_W1T);
    u16* W2T = (u16*)(ws + OFF_W2T);
    u16* Qb = (u16*)(ws + OFF_Q);
    u16* Kb = (u16*)(ws + OFF_K);
    u16* Vb = (u16*)(ws + OFF_V);
    u16* VTb = (u16*)(ws + OFF_VT);
    u16* attnbf = (u16*)(ws + OFF_ATTNO);
    u16* xbf = (u16*)(ws + OFF_XBF);
    u16* h1bf = (u16*)(ws + OFF_H1);
    float* partF = (float*)(ws + OFF_PART);

    float* out_f = (float*)d_out;
    float* probs = out_f + (size_t)BB * TT * DM;

    // 1. src -> bf16
    cvt_kernel<<<4096, 256, 0, stream>>>(src, srcbf, BB * TT * DM);
    // 2-5. weight transposes (fp32 [K][N] -> bf16 [N][K])
    transpose_kernel<0><<<dim3(N3 / 32, DM / 32, 1), 256, 0, stream>>>(Wqkv, WqkvT, DM, N3);
    transpose_kernel<0><<<dim3(DM / 32, DM / 32, 1), 256, 0, stream>>>(Wo, WoT, DM, DM);
    transpose_kernel<0><<<dim3(DFF / 32, DM / 32, 1), 256, 0, stream>>>(W1, W1T, DM, DFF);
    transpose_kernel<0><<<dim3(DM / 32, DFF / 32, 1), 256, 0, stream>>>(W2, W2T, DFF, DM);
    // 6. QKV GEMM with head-major scatter (K=1024 -> NT=32)
    gemm256_kernel<1, 32><<<dim3(N3 / 256, (BB * TT) / 256, 1), 512, 0, stream>>>(
        srcbf, WqkvT, bqkv, Qb, Kb, Vb, BB * TT, N3, DM);
    // 7. V -> V^T per head
    transpose_kernel<1><<<dim3(HD / 32, TT / 32, BB * NH), 256, 0, stream>>>(Vb, VTb, TT, HD);
    // 8. attention (probs -> d_out, attn_out bf16)
    attn_kernel<<<dim3(TT / 16, NH, BB), 512, 0, stream>>>(Qb, Kb, VTb, relb, temp, probs, attnbf);
    // 9. output projection, split-K=2 -> fp32 partials (Ksl=512 -> NT=16)
    gemm256_kernel<3, 16><<<dim3(DM / 256, (BB * TT) / 256, 2), 512, 0, stream>>>(
        attnbf, WoT, nullptr, partF, nullptr, nullptr, BB * TT, DM, DM);
    // 10. LN1: x = LN(src + bo + sum(part))
    ln_kernel<0, 2><<<BB * TT, 256, 0, stream>>>(src, nullptr, partF, bo, nullptr, g1, be1,
                                                 nullptr, xbf);
    // 11. FF1 + exact gelu (K=1024 -> NT=32)
    gemm256_kernel<2, 32><<<dim3(DFF / 256, (BB * TT) / 256, 1), 512, 0, stream>>>(
        xbf, W1T, b1, h1bf, nullptr, nullptr, BB * TT, DFF, DM);
    // 12. FF2, split-K=4 -> fp32 partials (Ksl=1024 -> NT=32)
    gemm256_kernel<3, 32><<<dim3(DM / 256, (BB * TT) / 256, 4), 512, 0, stream>>>(
        h1bf, W2T, nullptr, partF, nullptr, nullptr, BB * TT, DM, DFF);
    // 13. LN2 -> d_out
    ln_kernel<1, 4><<<BB * TT, 256, 0, stream>>>(nullptr, xbf, partF, b2, ffs, g2, be2,
                                                 out_f, nullptr);
}